// Round 1
// baseline (8533.751 us; speedup 1.0000x reference)
//
#include <hip/hip_runtime.h>
#include <hip/hip_bf16.h>
#include <stdint.h>

// ---------------------------------------------------------------------------
// LSTM: B=64, S=512, D_IN=1024, HID=4096, HS=1024, fp32 in/out.
// Strategy:
//   1) cvt x, wx, wh -> bf16
//   2) pregemm (MFMA bf16, m97-style 128x128 tile): xg2 = x@wx.T + bx + bh,
//      stored bf16 in recurrence-friendly layout [t][wg][bloc][n]
//   3) persistent recurrent kernel: 4 independent groups (16 batches each) x
//      64 WGs; wh fragments live in registers; flag-based 64-WG barrier/step.
// ---------------------------------------------------------------------------

typedef __attribute__((ext_vector_type(8))) short short8;
typedef __attribute__((ext_vector_type(4))) float floatx4;

#define S_LEN 512
#define BATCH 64
#define DIN   1024
#define HID   4096
#define HS    1024

// workspace byte offsets (total ~336.3 MB)
#define XG2_OFF   0ull                      // ushort[512*256*16*64] = 256 MB
#define XBF_OFF   268435456ull              // ushort[32768*1024]    = 64 MB
#define WXBF_OFF  335544320ull              // ushort[4096*1024]     = 8 MB
#define WHBF_OFF  343932928ull              // ushort[4096*1024]     = 8 MB
#define HBUF_OFF  352321536ull              // ushort[2][64][1024]   = 256 KB
#define FLAG_OFF  352583680ull              // int[256*16]           = 16 KB

__device__ __forceinline__ unsigned short f2bf(float f) {
  unsigned int u = __float_as_uint(f);
  u += 0x7fffu + ((u >> 16) & 1u);        // RNE
  return (unsigned short)(u >> 16);
}
__device__ __forceinline__ float bf2f(unsigned short s) {
  return __uint_as_float(((unsigned int)s) << 16);
}

__device__ __forceinline__ void async_ld16(const void* g, const void* l) {
  __builtin_amdgcn_global_load_lds(
      (const __attribute__((address_space(1))) unsigned int*)g,
      (__attribute__((address_space(3))) unsigned int*)l,
      16, 0, 0);
}

__device__ __forceinline__ float sigmoidf_(float x) {
  return 1.0f / (1.0f + __expf(-x));
}
__device__ __forceinline__ float tanhf_(float x) {
  return 2.0f / (1.0f + __expf(-2.0f * x)) - 1.0f;
}

// --------------------------- fp32 -> bf16 cast ------------------------------
__global__ void cvt_kernel(const float* __restrict__ src,
                           unsigned short* __restrict__ dst, int n4) {
  int i = blockIdx.x * blockDim.x + threadIdx.x;
  if (i < n4) {
    float4 v = ((const float4*)src)[i];
    ushort4 o;
    o.x = f2bf(v.x); o.y = f2bf(v.y); o.z = f2bf(v.z); o.w = f2bf(v.w);
    ((ushort4*)dst)[i] = o;
  }
}

__global__ void zero_kernel(unsigned int* __restrict__ p, int n) {
  int i = blockIdx.x * blockDim.x + threadIdx.x;
  if (i < n) p[i] = 0u;
}

// ------------------------------- pre-GEMM -----------------------------------
// C[m][g] = sum_k x_bf[m][k] * wx_bf[g][k] + bx[g] + bh[g]   (m = b*512 + t)
// stored bf16 at xg2[((t*256 + wg)*16 + bloc)*64 + n],
//   wg = (b>>4)*64 + ((g&1023)>>4),  bloc = b&15,  n = (g>>10)*16 + (g&15)
__global__ __launch_bounds__(256) void pregemm_kernel(
    const unsigned short* __restrict__ A,    // [32768][1024] bf16
    const unsigned short* __restrict__ Bw,   // [4096][1024]  bf16 (B^T layout)
    const float* __restrict__ bx, const float* __restrict__ bh,
    unsigned short* __restrict__ xg2) {
  __shared__ unsigned short As[128 * 32];
  __shared__ unsigned short Bs[128 * 32];
  const int tid = threadIdx.x;
  const int lane = tid & 63, wv = tid >> 6;
  const int l15 = lane & 15, lq = lane >> 4;
  const int m0 = blockIdx.y * 128, n0 = blockIdx.x * 128;
  const int wm = (wv >> 1) * 64, wn = (wv & 1) * 64;

  floatx4 acc[4][4];
#pragma unroll
  for (int i = 0; i < 4; i++)
#pragma unroll
    for (int j = 0; j < 4; j++) acc[i][j] = (floatx4){0.f, 0.f, 0.f, 0.f};

  for (int k0 = 0; k0 < DIN; k0 += 32) {
#pragma unroll
    for (int q = 0; q < 2; q++) {
      const int e = (q * 256 + tid) * 8;      // element within 128x32 tile
      const int r = e >> 5, c = e & 31;
      async_ld16(A + (size_t)(m0 + r) * DIN + k0 + c, (unsigned short*)As + e);
      async_ld16(Bw + (size_t)(n0 + r) * DIN + k0 + c, (unsigned short*)Bs + e);
    }
    __syncthreads();
    short8 af[4], bfv[4];
#pragma unroll
    for (int i = 0; i < 4; i++)
      af[i] = *(const short8*)&As[(wm + i * 16 + l15) * 32 + lq * 8];
#pragma unroll
    for (int j = 0; j < 4; j++)
      bfv[j] = *(const short8*)&Bs[(wn + j * 16 + l15) * 32 + lq * 8];
#pragma unroll
    for (int i = 0; i < 4; i++)
#pragma unroll
      for (int j = 0; j < 4; j++)
        acc[i][j] = __builtin_amdgcn_mfma_f32_16x16x32_bf16(af[i], bfv[j],
                                                            acc[i][j], 0, 0, 0);
    __syncthreads();
  }

#pragma unroll
  for (int j = 0; j < 4; j++) {
    const int col = n0 + wn + j * 16 + l15;
    const float bias = bx[col] + bh[col];
    const int gate = col >> 10;
    const int c1 = col & 1023;
    const int wslice = c1 >> 4, cc = c1 & 15;
    const int n_idx = gate * 16 + cc;
#pragma unroll
    for (int i = 0; i < 4; i++) {
#pragma unroll
      for (int r = 0; r < 4; r++) {
        const int m = m0 + wm + i * 16 + lq * 4 + r;
        const int b = m >> 9, t = m & 511;
        const size_t idx =
            ((size_t)(t * 256 + ((b >> 4) * 64 + wslice)) * 16 + (b & 15)) * 64 +
            n_idx;
        xg2[idx] = f2bf(acc[i][j][r] + bias);
      }
    }
  }
}

// ------------------------------ recurrence ----------------------------------
// 256 WGs = 4 groups x 64 slices. Group g handles batches [g*16, g*16+16).
// WG slice w holds wh rows {gate*1024 + w*16 + c} (gate 0..3, c 0..15) in
// REGISTERS (4 waves split K: wave kq holds k in [kq*256, kq*256+256)).
__global__ __launch_bounds__(256, 1) void lstm_kernel(
    const unsigned short* __restrict__ whbf,  // [4096][1024] bf16
    const unsigned short* __restrict__ xg2,
    unsigned short* __restrict__ hbuf,        // [2][64][1024] bf16
    int* __restrict__ flags,                  // [256*16]
    float* __restrict__ out,                  // [64][512][1024]
    float* __restrict__ outh, float* __restrict__ outc) {
  __shared__ float gpart[4 * 16 * 68];  // [kq][bloc][n] padded

  const int tid = threadIdx.x;
  const int lane = tid & 63, kq = tid >> 6;
  const int l15 = lane & 15, lq = lane >> 4;
  const int wg = blockIdx.x;
  const int group = wg >> 6, wslice = wg & 63;
  const int j0 = wslice * 16;

  // B fragments: bfrag[j][kc] covers gate j, cols j0..j0+15, k = kq*256+kc*32+..
  short8 bfrag[4][8];
#pragma unroll
  for (int j = 0; j < 4; j++) {
    const size_t grow = (size_t)(j * 1024 + j0 + l15) * HS;
#pragma unroll
    for (int kc = 0; kc < 8; kc++)
      bfrag[j][kc] = *(const short8*)&whbf[grow + kq * 256 + kc * 32 + lq * 8];
  }

  const int eb = tid >> 4;  // bloc 0..15 (elementwise phase)
  const int ec = tid & 15;  // col within slice
  const int gb = group * 16 + eb;  // global batch
  float c_state = 0.0f;

  // xg prefetch for t=0
  unsigned short xv0, xv1, xv2, xv3;
  {
    const unsigned short* xr = xg2 + ((size_t)(wg)*16 + eb) * 64 + ec;
    xv0 = xr[0]; xv1 = xr[16]; xv2 = xr[32]; xv3 = xr[48];
  }

  const int arow = (group * 16 + l15) * HS + kq * 256 + lq * 8;

  for (int t = 0; t < S_LEN; t++) {
    const unsigned short* hp = hbuf + (size_t)(t & 1) * (BATCH * HS);
    short8 a[8];
#pragma unroll
    for (int kc = 0; kc < 8; kc++)
      a[kc] = *(const short8*)&hp[arow + kc * 32];
    floatx4 acc0 = (floatx4){0.f, 0.f, 0.f, 0.f};
    floatx4 acc1 = acc0, acc2 = acc0, acc3 = acc0;
#pragma unroll
    for (int kc = 0; kc < 8; kc++) {
      acc0 = __builtin_amdgcn_mfma_f32_16x16x32_bf16(a[kc], bfrag[0][kc], acc0, 0, 0, 0);
      acc1 = __builtin_amdgcn_mfma_f32_16x16x32_bf16(a[kc], bfrag[1][kc], acc1, 0, 0, 0);
      acc2 = __builtin_amdgcn_mfma_f32_16x16x32_bf16(a[kc], bfrag[2][kc], acc2, 0, 0, 0);
      acc3 = __builtin_amdgcn_mfma_f32_16x16x32_bf16(a[kc], bfrag[3][kc], acc3, 0, 0, 0);
    }
#pragma unroll
    for (int r = 0; r < 4; r++) {
      const int row = (kq * 16 + lq * 4 + r) * 68;
      gpart[row + 0 * 16 + l15] = acc0[r];
      gpart[row + 1 * 16 + l15] = acc1[r];
      gpart[row + 2 * 16 + l15] = acc2[r];
      gpart[row + 3 * 16 + l15] = acc3[r];
    }
    __syncthreads();

    float g0 = bf2f(xv0), g1 = bf2f(xv1), g2 = bf2f(xv2), g3 = bf2f(xv3);
#pragma unroll
    for (int q = 0; q < 4; q++) {
      const float* gp = &gpart[(q * 16 + eb) * 68 + ec];
      g0 += gp[0]; g1 += gp[16]; g2 += gp[32]; g3 += gp[48];
    }
    const float i_ = sigmoidf_(g0);
    const float f_ = sigmoidf_(g1);
    const float gg = tanhf_(g2);
    const float o_ = sigmoidf_(g3);
    c_state = f_ * c_state + i_ * gg;
    const float h = o_ * tanhf_(c_state);

    __builtin_nontemporal_store(
        f2bf(h), &hbuf[(size_t)((t + 1) & 1) * (BATCH * HS) + gb * HS + j0 + ec]);
    __builtin_nontemporal_store(h, &out[((size_t)gb * S_LEN + t) * HS + j0 + ec]);

    if (t + 1 < S_LEN) {  // prefetch next xg chunk (independent of barrier)
      const unsigned short* xr =
          xg2 + ((size_t)((t + 1) * 256 + wg) * 16 + eb) * 64 + ec;
      xv0 = xr[0]; xv1 = xr[16]; xv2 = xr[32]; xv3 = xr[48];
    }

    if (t == S_LEN - 1) {
      outh[gb * HS + j0 + ec] = h;
      outc[gb * HS + j0 + ec] = c_state;
      break;  // no barrier needed after last step
    }

    __syncthreads();  // drains vmcnt: h stores complete (NT -> LLC)
    if (tid == 0) {
      __builtin_amdgcn_fence(__ATOMIC_RELEASE, "agent");
      __hip_atomic_store(&flags[wg * 16], t + 1, __ATOMIC_RELAXED,
                         __HIP_MEMORY_SCOPE_AGENT);
    }
    if (kq == 0) {  // wave 0: 64 lanes poll the group's 64 flags in parallel
      const int tgt = t + 1;
      int* fp = &flags[(group * 64 + lane) * 16];
      while (true) {
        int v = __hip_atomic_load(fp, __ATOMIC_RELAXED, __HIP_MEMORY_SCOPE_AGENT);
        if (__all(v >= tgt)) break;
        __builtin_amdgcn_s_sleep(1);
      }
    }
    __syncthreads();
    __builtin_amdgcn_fence(__ATOMIC_ACQUIRE, "agent");  // invalidate stale L2/L1
  }
}

// ------------------------------- launcher -----------------------------------
extern "C" void kernel_launch(void* const* d_in, const int* in_sizes, int n_in,
                              void* d_out, int out_size, void* d_ws,
                              size_t ws_size, hipStream_t stream) {
  const float* x  = (const float*)d_in[0];
  const float* wx = (const float*)d_in[1];
  const float* wh = (const float*)d_in[2];
  const float* bx = (const float*)d_in[3];
  const float* bh = (const float*)d_in[4];
  char* ws = (char*)d_ws;
  unsigned short* xg2  = (unsigned short*)(ws + XG2_OFF);
  unsigned short* xbf  = (unsigned short*)(ws + XBF_OFF);
  unsigned short* wxbf = (unsigned short*)(ws + WXBF_OFF);
  unsigned short* whbf = (unsigned short*)(ws + WHBF_OFF);
  unsigned short* hbuf = (unsigned short*)(ws + HBUF_OFF);
  int* flags = (int*)(ws + FLAG_OFF);

  float* out  = (float*)d_out;
  float* outh = out + (size_t)BATCH * S_LEN * HS;
  float* outc = outh + BATCH * HS;

  cvt_kernel<<<(33554432 / 4) / 256, 256, 0, stream>>>(x, xbf, 33554432 / 4);
  cvt_kernel<<<(4194304 / 4) / 256, 256, 0, stream>>>(wx, wxbf, 4194304 / 4);
  cvt_kernel<<<(4194304 / 4) / 256, 256, 0, stream>>>(wh, whbf, 4194304 / 4);
  // zero hbuf (262144 B) + flags (16384 B) contiguous = 69632 uints
  zero_kernel<<<(69632 + 255) / 256, 256, 0, stream>>>(
      (unsigned int*)(ws + HBUF_OFF), 69632);

  dim3 pg(HID / 128, (BATCH * S_LEN) / 128);  // 32 x 256
  pregemm_kernel<<<pg, 256, 0, stream>>>(xbf, wxbf, bx, bh, xg2);

  lstm_kernel<<<256, 256, 0, stream>>>(whbf, xg2, hbuf, flags, out, outh, outc);
}

// Round 3
// 2363.836 us; speedup vs baseline: 3.6101x; 3.6101x over previous
//
#include <hip/hip_runtime.h>
#include <hip/hip_bf16.h>
#include <stdint.h>

// ---------------------------------------------------------------------------
// LSTM: B=64, S=512, D_IN=1024, HID=4096, HS=1024, fp32 in/out.
//   1) cvt x, wx, wh -> bf16
//   2) pregemm (MFMA bf16, 128x128 tile): xg2 = x@wx.T + bx + bh, bf16,
//      recurrence-friendly layout [t][wg][bloc][n]
//   3) persistent recurrent kernel: 4 groups (16 batches) x 64 WGs; wh
//      fragments register/AGPR-resident; NO cache-maintenance fences --
//      all cross-WG data (h, flags) moves via sc0+sc1 (LLC-coherent) ops,
//      per-wave producer-subset flag polling.
// R3 fix: register-tied s_waitcnt between asm h-loads and MFMA use. The
// MFMA intrinsics have no memory/asm ordering; without the register tie the
// scheduler hoisted them above the waitcnt -> consumed in-flight VGPRs (NaN).
// ---------------------------------------------------------------------------

typedef __attribute__((ext_vector_type(8))) short short8;
typedef __attribute__((ext_vector_type(4))) float floatx4;

#define S_LEN 512
#define BATCH 64
#define DIN   1024
#define HID   4096
#define HS    1024

// workspace byte offsets (total ~336.3 MB)
#define XG2_OFF   0ull                      // ushort[512*256*16*64] = 256 MB
#define XBF_OFF   268435456ull              // ushort[32768*1024]    = 64 MB
#define WXBF_OFF  335544320ull              // ushort[4096*1024]     = 8 MB
#define WHBF_OFF  343932928ull              // ushort[4096*1024]     = 8 MB
#define HBUF_OFF  352321536ull              // ushort[2][64][1024]   = 256 KB
#define FLAG_OFF  352583680ull              // int[256*16]           = 16 KB

__device__ __forceinline__ unsigned short f2bf(float f) {
  unsigned int u = __float_as_uint(f);
  u += 0x7fffu + ((u >> 16) & 1u);        // RNE
  return (unsigned short)(u >> 16);
}
__device__ __forceinline__ float bf2f(unsigned short s) {
  return __uint_as_float(((unsigned int)s) << 16);
}

__device__ __forceinline__ void async_ld16(const void* g, const void* l) {
  __builtin_amdgcn_global_load_lds(
      (const __attribute__((address_space(1))) unsigned int*)g,
      (__attribute__((address_space(3))) unsigned int*)l,
      16, 0, 0);
}

// L2-bypassing (sc0 sc1) 16B load -> goes straight to LLC; no staleness,
// no per-step cache invalidates needed.
__device__ __forceinline__ short8 load16_llc(const void* p) {
  floatx4 r;
  asm volatile("global_load_dwordx4 %0, %1, off sc0 sc1"
               : "=v"(r) : "v"(p) : "memory");
  return __builtin_bit_cast(short8, r);
}
// L2-bypassing 2B store (write-through to LLC).
__device__ __forceinline__ void store2_llc(void* p, unsigned int v) {
  asm volatile("global_store_short %0, %1, off sc0 sc1"
               :: "v"(p), "v"(v) : "memory");
}
__device__ __forceinline__ void wait_vm0() {
  asm volatile("s_waitcnt vmcnt(0)" ::: "memory");
}

__device__ __forceinline__ float sigmoidf_(float x) {
  return 1.0f / (1.0f + __expf(-x));
}
__device__ __forceinline__ float tanhf_(float x) {
  return 2.0f / (1.0f + __expf(-2.0f * x)) - 1.0f;
}

// --------------------------- fp32 -> bf16 cast ------------------------------
__global__ void cvt_kernel(const float* __restrict__ src,
                           unsigned short* __restrict__ dst, int n4) {
  int i = blockIdx.x * blockDim.x + threadIdx.x;
  if (i < n4) {
    float4 v = ((const float4*)src)[i];
    ushort4 o;
    o.x = f2bf(v.x); o.y = f2bf(v.y); o.z = f2bf(v.z); o.w = f2bf(v.w);
    ((ushort4*)dst)[i] = o;
  }
}

__global__ void zero_kernel(unsigned int* __restrict__ p, int n) {
  int i = blockIdx.x * blockDim.x + threadIdx.x;
  if (i < n) p[i] = 0u;
}

// ------------------------------- pre-GEMM -----------------------------------
// C[m][g] = sum_k x_bf[m][k] * wx_bf[g][k] + bx[g] + bh[g]   (m = b*512 + t)
// stored bf16 at xg2[((t*256 + wg)*16 + bloc)*64 + n],
//   wg = (b>>4)*64 + ((g&1023)>>4),  bloc = b&15,  n = (g>>10)*16 + (g&15)
__global__ __launch_bounds__(256) void pregemm_kernel(
    const unsigned short* __restrict__ A,    // [32768][1024] bf16
    const unsigned short* __restrict__ Bw,   // [4096][1024]  bf16 (B^T layout)
    const float* __restrict__ bx, const float* __restrict__ bh,
    unsigned short* __restrict__ xg2) {
  __shared__ unsigned short As[128 * 32];
  __shared__ unsigned short Bs[128 * 32];
  const int tid = threadIdx.x;
  const int lane = tid & 63, wv = tid >> 6;
  const int l15 = lane & 15, lq = lane >> 4;
  const int m0 = blockIdx.y * 128, n0 = blockIdx.x * 128;
  const int wm = (wv >> 1) * 64, wn = (wv & 1) * 64;

  floatx4 acc[4][4];
#pragma unroll
  for (int i = 0; i < 4; i++)
#pragma unroll
    for (int j = 0; j < 4; j++) acc[i][j] = (floatx4){0.f, 0.f, 0.f, 0.f};

  for (int k0 = 0; k0 < DIN; k0 += 32) {
#pragma unroll
    for (int q = 0; q < 2; q++) {
      const int e = (q * 256 + tid) * 8;      // element within 128x32 tile
      const int r = e >> 5, c = e & 31;
      async_ld16(A + (size_t)(m0 + r) * DIN + k0 + c, (unsigned short*)As + e);
      async_ld16(Bw + (size_t)(n0 + r) * DIN + k0 + c, (unsigned short*)Bs + e);
    }
    __syncthreads();
    short8 af[4], bfv[4];
#pragma unroll
    for (int i = 0; i < 4; i++)
      af[i] = *(const short8*)&As[(wm + i * 16 + l15) * 32 + lq * 8];
#pragma unroll
    for (int j = 0; j < 4; j++)
      bfv[j] = *(const short8*)&Bs[(wn + j * 16 + l15) * 32 + lq * 8];
#pragma unroll
    for (int i = 0; i < 4; i++)
#pragma unroll
      for (int j = 0; j < 4; j++)
        acc[i][j] = __builtin_amdgcn_mfma_f32_16x16x32_bf16(af[i], bfv[j],
                                                            acc[i][j], 0, 0, 0);
    __syncthreads();
  }

#pragma unroll
  for (int j = 0; j < 4; j++) {
    const int col = n0 + wn + j * 16 + l15;
    const float bias = bx[col] + bh[col];
    const int gate = col >> 10;
    const int c1 = col & 1023;
    const int wslice = c1 >> 4, cc = c1 & 15;
    const int n_idx = gate * 16 + cc;
#pragma unroll
    for (int i = 0; i < 4; i++) {
#pragma unroll
      for (int r = 0; r < 4; r++) {
        const int m = m0 + wm + i * 16 + lq * 4 + r;
        const int b = m >> 9, t = m & 511;
        const size_t idx =
            ((size_t)(t * 256 + ((b >> 4) * 64 + wslice)) * 16 + (b & 15)) * 64 +
            n_idx;
        xg2[idx] = f2bf(acc[i][j][r] + bias);
      }
    }
  }
}

// ------------------------------ recurrence ----------------------------------
// 256 WGs = 4 groups x 64 slices. Group g handles batches [g*16, g*16+16).
// WG slice w holds wh rows {gate*1024 + w*16 + c} in registers/AGPRs
// (4 waves split K: wave kq holds k in [kq*256, kq*256+256)).
// Cross-WG h exchange entirely via sc0+sc1 ops through LLC; wave kq polls
// only its 16 producer WGs' flags. The 4 waves' poll sets jointly cover all
// 64 group flags and join at the first __syncthreads (before any h' write),
// so flag>=t for ALL producers holds before buffer (t+1)&1 is overwritten
// (WAR-safe); flag=t also implies that WG's step-t-1 reads+writes drained
// (RAW-safe). NO agent fences anywhere in the loop.
__global__ __launch_bounds__(256, 1) void lstm_kernel(
    const unsigned short* __restrict__ whbf,  // [4096][1024] bf16
    const unsigned short* __restrict__ xg2,
    unsigned short* __restrict__ hbuf,        // [2][64][1024] bf16
    int* __restrict__ flags,                  // [256*16]
    float* __restrict__ out,                  // [64][512][1024]
    float* __restrict__ outh, float* __restrict__ outc) {
  __shared__ float gpart[4 * 16 * 68];  // [kq][bloc][n] padded

  const int tid = threadIdx.x;
  const int lane = tid & 63, kq = tid >> 6;
  const int l15 = lane & 15, lq = lane >> 4;
  const int wg = blockIdx.x;
  const int group = wg >> 6, wslice = wg & 63;
  const int j0 = wslice * 16;

  // B fragments: bfrag[j][kc] covers gate j, cols j0..j0+15, k = kq*256+kc*32+..
  short8 bfrag[4][8];
#pragma unroll
  for (int j = 0; j < 4; j++) {
    const size_t grow = (size_t)(j * 1024 + j0 + l15) * HS;
#pragma unroll
    for (int kc = 0; kc < 8; kc++)
      bfrag[j][kc] = *(const short8*)&whbf[grow + kq * 256 + kc * 32 + lq * 8];
  }

  const int eb = tid >> 4;         // bloc 0..15 (elementwise phase)
  const int ec = tid & 15;         // col within slice
  const int gb = group * 16 + eb;  // global batch
  float c_state = 0.0f;

  const int arow = (group * 16 + l15) * HS + kq * 256 + lq * 8;
  // wave kq consumes h cols [kq*256, kq*256+256) -> producer WGs kq*16..+16
  int* fp = flags + (size_t)(group * 64 + kq * 16 + l15) * 16;

  for (int t = 0; t < S_LEN; t++) {
    if (t > 0) {
      // per-wave producer-subset poll (16 lanes active, throttled)
      while (true) {
        int v = t;
        if (lq == 0)
          v = __hip_atomic_load(fp, __ATOMIC_RELAXED, __HIP_MEMORY_SCOPE_AGENT);
        if (__all(v >= t)) break;
        __builtin_amdgcn_s_sleep(2);
      }
    }

    // xg loads for this step (normal cached; latency hidden under h loads)
    const unsigned short* xr = xg2 + ((size_t)(t * 256 + wg) * 16 + eb) * 64 + ec;
    const unsigned short xv0 = xr[0], xv1 = xr[16], xv2 = xr[32], xv3 = xr[48];

    // h loads: sc0+sc1 direct from LLC (writer wrote through)
    const unsigned short* hp = hbuf + (size_t)(t & 1) * (BATCH * HS) + arow;
    short8 a[8];
#pragma unroll
    for (int kc = 0; kc < 8; kc++) a[kc] = load16_llc(&hp[kc * 32]);
    // Register-tied drain: MFMA below data-depends on these operands, so it
    // cannot be scheduled above this waitcnt (R2's NaN bug).
    asm volatile("s_waitcnt vmcnt(0)"
                 : "+v"(a[0]), "+v"(a[1]), "+v"(a[2]), "+v"(a[3]),
                   "+v"(a[4]), "+v"(a[5]), "+v"(a[6]), "+v"(a[7])
                 :: "memory");

    floatx4 acc0 = (floatx4){0.f, 0.f, 0.f, 0.f};
    floatx4 acc1 = acc0, acc2 = acc0, acc3 = acc0;
#pragma unroll
    for (int kc = 0; kc < 8; kc++) {
      acc0 = __builtin_amdgcn_mfma_f32_16x16x32_bf16(a[kc], bfrag[0][kc], acc0, 0, 0, 0);
      acc1 = __builtin_amdgcn_mfma_f32_16x16x32_bf16(a[kc], bfrag[1][kc], acc1, 0, 0, 0);
      acc2 = __builtin_amdgcn_mfma_f32_16x16x32_bf16(a[kc], bfrag[2][kc], acc2, 0, 0, 0);
      acc3 = __builtin_amdgcn_mfma_f32_16x16x32_bf16(a[kc], bfrag[3][kc], acc3, 0, 0, 0);
    }
#pragma unroll
    for (int r = 0; r < 4; r++) {
      const int row = (kq * 16 + lq * 4 + r) * 68;
      gpart[row + 0 * 16 + l15] = acc0[r];
      gpart[row + 1 * 16 + l15] = acc1[r];
      gpart[row + 2 * 16 + l15] = acc2[r];
      gpart[row + 3 * 16 + l15] = acc3[r];
    }
    __syncthreads();

    float g0 = bf2f(xv0), g1 = bf2f(xv1), g2 = bf2f(xv2), g3 = bf2f(xv3);
#pragma unroll
    for (int q = 0; q < 4; q++) {
      const float* gp = &gpart[(q * 16 + eb) * 68 + ec];
      g0 += gp[0]; g1 += gp[16]; g2 += gp[32]; g3 += gp[48];
    }
    const float i_ = sigmoidf_(g0);
    const float f_ = sigmoidf_(g1);
    const float gg = tanhf_(g2);
    const float o_ = sigmoidf_(g3);
    c_state = f_ * c_state + i_ * gg;
    const float h = o_ * tanhf_(c_state);

    // h' write-through to LLC + out store (both drain before flag)
    store2_llc(&hbuf[(size_t)((t + 1) & 1) * (BATCH * HS) + gb * HS + j0 + ec],
               (unsigned int)f2bf(h));
    __builtin_nontemporal_store(h, &out[((size_t)gb * S_LEN + t) * HS + j0 + ec]);

    if (t == S_LEN - 1) {
      outh[gb * HS + j0 + ec] = h;
      outc[gb * HS + j0 + ec] = c_state;
      break;  // nobody waits on the last flag
    }

    wait_vm0();           // all this wave's h' stores are in LLC
    __syncthreads();      // -> all 4 waves' h' stores are in LLC
    if (tid == 0)
      __hip_atomic_store(&flags[wg * 16], t + 1, __ATOMIC_RELAXED,
                         __HIP_MEMORY_SCOPE_AGENT);
  }
}

// ------------------------------- launcher -----------------------------------
extern "C" void kernel_launch(void* const* d_in, const int* in_sizes, int n_in,
                              void* d_out, int out_size, void* d_ws,
                              size_t ws_size, hipStream_t stream) {
  const float* x  = (const float*)d_in[0];
  const float* wx = (const float*)d_in[1];
  const float* wh = (const float*)d_in[2];
  const float* bx = (const float*)d_in[3];
  const float* bh = (const float*)d_in[4];
  char* ws = (char*)d_ws;
  unsigned short* xg2  = (unsigned short*)(ws + XG2_OFF);
  unsigned short* xbf  = (unsigned short*)(ws + XBF_OFF);
  unsigned short* wxbf = (unsigned short*)(ws + WXBF_OFF);
  unsigned short* whbf = (unsigned short*)(ws + WHBF_OFF);
  unsigned short* hbuf = (unsigned short*)(ws + HBUF_OFF);
  int* flags = (int*)(ws + FLAG_OFF);

  float* out  = (float*)d_out;
  float* outh = out + (size_t)BATCH * S_LEN * HS;
  float* outc = outh + BATCH * HS;

  cvt_kernel<<<(33554432 / 4) / 256, 256, 0, stream>>>(x, xbf, 33554432 / 4);
  cvt_kernel<<<(4194304 / 4) / 256, 256, 0, stream>>>(wx, wxbf, 4194304 / 4);
  cvt_kernel<<<(4194304 / 4) / 256, 256, 0, stream>>>(wh, whbf, 4194304 / 4);
  // zero hbuf (262144 B) + flags (16384 B) contiguous = 69632 uints
  zero_kernel<<<(69632 + 255) / 256, 256, 0, stream>>>(
      (unsigned int*)(ws + HBUF_OFF), 69632);

  dim3 pg(HID / 128, (BATCH * S_LEN) / 128);  // 32 x 256
  pregemm_kernel<<<pg, 256, 0, stream>>>(xbf, wxbf, bx, bh, xg2);

  lstm_kernel<<<256, 256, 0, stream>>>(whbf, xg2, hbuf, flags, out, outh, outc);
}